// Round 11
// baseline (531.236 us; speedup 1.0000x reference)
//
#include <hip/hip_runtime.h>
#include <hip/hip_bf16.h>
#include <cfloat>

#define CH   1024
#define HW   4096
#define NSVD 500
#define TFR  3
#define SREF 2

typedef __attribute__((ext_vector_type(4))) float f32x4;
typedef __attribute__((ext_vector_type(4))) unsigned int u32x4;
typedef __attribute__((ext_vector_type(8))) short short8;

// ---------------------------------------------------------------------------
// Split-bf16 planes in BLOCKED layout (gload_lds-friendly):
//   plane[t][cb][kgrp][cl][kp4] u32. K-tile slab (16 KB) contiguous.
// 3-PASS numerics (hh + h*lo(B) + lo(A)*h): proven vote-safe.
// simg: phase-split with READ-AHEAD (fragment ds_reads for phase p+1 issued
//   before phase p's MFMA cluster) -> ds_read latency hides under MFMA.
//   Accumulation order bit-identical to R9/R10.
// ws (float units): fh 0 / fl 6,291,456 / invn 12,582,912 / invc 12,595,200 /
//   protos 12,607,552 / proto 12,611,648 / am 12,612,672 (2*4096 u64) /
//   part 12,629,056 (8*2048) -> end 12,645,440 (proven envelope)
// d_out scratch: Ach 0, Acl 786,432, coef 1,572,864, Xd 5,767,168
// ---------------------------------------------------------------------------

__device__ inline unsigned bfr(float x) {        // fp32 -> bf16 bits, RNE
  unsigned u = __float_as_uint(x);
  return (u + 0x7fffu + ((u >> 16) & 1u)) >> 16;
}
__device__ inline float lores(float x, unsigned h) {
  return x - __uint_as_float(h << 16);
}
__device__ inline float vlo(unsigned ph, unsigned pl) {
  return __uint_as_float(ph << 16) + __uint_as_float(pl << 16);
}
__device__ inline float vhi(unsigned ph, unsigned pl) {
  return __uint_as_float(ph & 0xFFFF0000u) + __uint_as_float(pl & 0xFFFF0000u);
}

// Column L2 norms over C, layout (t, c, n)
__global__ __launch_bounds__(256) void colnorm_k(const float* __restrict__ src,
                                                 float* __restrict__ inv) {
  int blk = blockIdx.x;
  int t = blk >> 6;
  int n0 = (blk & 63) * 64;
  int tid = threadIdx.x;
  int nl = tid & 63, r = tid >> 6;
  const float* base = src + (size_t)t * CH * HW + n0 + nl;
  float s = 0.f;
  for (int c = r; c < CH; c += 4) {
    float v = base[(size_t)c * HW];
    s += v * v;
  }
  __shared__ float red[256];
  red[tid] = s;
  __syncthreads();
  if (r == 0) {
    float tot = red[nl] + red[nl + 64] + red[nl + 128] + red[nl + 192];
    inv[t * HW + n0 + nl] = 1.0f / fmaxf(sqrtf(tot), 1e-12f);
  }
}

// blocked planes <- pack(src[t,c,n]*inv[t,n]); thread owns (t, kgrp, n)
__global__ __launch_bounds__(256) void scale_pack_k(const float* __restrict__ src,
                                                    const float* __restrict__ inv,
                                                    unsigned* __restrict__ Gh,
                                                    unsigned* __restrict__ Gl) {
  int gid = blockIdx.x * 256 + threadIdx.x;
  int lt = gid >> 19;
  int kg = (gid >> 12) & 127;
  int n = gid & 4095;
  const float* s0 = src + ((size_t)lt * CH + kg * 8) * HW + n;
  float w = inv[lt * HW + n];
  unsigned oh[4], ol[4];
#pragma unroll
  for (int j = 0; j < 4; j++) {
    float a = s0[(size_t)(2 * j) * HW] * w;
    float b = s0[(size_t)(2 * j + 1) * HW] * w;
    unsigned ha = bfr(a), hb = bfr(b);
    oh[j] = ha | (hb << 16);
    ol[j] = bfr(lores(a, ha)) | (bfr(lores(b, hb)) << 16);
  }
  size_t vi = (((size_t)lt * 16 + (n >> 8)) * 128 + kg) * 256 + (n & 255);
  *reinterpret_cast<u32x4*>(Gh + vi * 4) = *reinterpret_cast<u32x4*>(oh);
  *reinterpret_cast<u32x4*>(Gl + vi * 4) = *reinterpret_cast<u32x4*>(ol);
}

// Acomb cols 0..1023: P = I - basis@basis^T, blocked write
__global__ __launch_bounds__(256) void proj_pack_k(const float* __restrict__ bas,
                                                   unsigned* __restrict__ Ah,
                                                   unsigned* __restrict__ Al) {
  int m0 = blockIdx.x * 64, n0 = blockIdx.y * 64;
  int tid = threadIdx.x;
  int tx = tid & 15, ty = tid >> 4;
  int lm = tid & 63, lk = tid >> 6;
  __shared__ float As[16][64];
  __shared__ float Bs[16][64];
  float acc[4][4] = {};
  for (int k0 = 0; k0 < 512; k0 += 16) {
#pragma unroll
    for (int i = 0; i < 4; i++) {
      int k = k0 + lk * 4 + i;
      As[lk * 4 + i][lm] = (k < NSVD) ? bas[(size_t)(m0 + lm) * NSVD + k] : 0.f;
      Bs[lk * 4 + i][lm] = (k < NSVD) ? bas[(size_t)(n0 + lm) * NSVD + k] : 0.f;
    }
    __syncthreads();
#pragma unroll
    for (int kk = 0; kk < 16; kk++) {
      float a[4], b[4];
#pragma unroll
      for (int i = 0; i < 4; i++) a[i] = As[kk][ty * 4 + i];
#pragma unroll
      for (int j = 0; j < 4; j++) b[j] = Bs[kk][tx * 4 + j];
#pragma unroll
      for (int i = 0; i < 4; i++)
#pragma unroll
        for (int j = 0; j < 4; j++) acc[i][j] += a[i] * b[j];
    }
    __syncthreads();
  }
#pragma unroll
  for (int jp = 0; jp < 2; jp++) {
    int r = n0 / 2 + tx * 2 + jp;     // kpair
#pragma unroll
    for (int i = 0; i < 4; i++) {
      int c = m0 + ty * 4 + i;        // column
      float va = ((c == 2 * r) ? 1.0f : 0.0f) - acc[i][2 * jp];
      float vb = ((c == 2 * r + 1) ? 1.0f : 0.0f) - acc[i][2 * jp + 1];
      unsigned ha = bfr(va), hb = bfr(vb);
      size_t vi = ((size_t)((c >> 8) * 128 + (r >> 2)) * 256 + (c & 255)) * 4 + (r & 3);
      Ah[vi] = ha | (hb << 16);
      Al[vi] = bfr(lores(va, ha)) | (bfr(lores(vb, hb)) << 16);
    }
  }
}

// Acomb cols 1024..1535: basis zero-padded to 512 svd rows
__global__ __launch_bounds__(256) void pack_basis_k(const float* __restrict__ bas,
                                                    unsigned* __restrict__ Ah,
                                                    unsigned* __restrict__ Al) {
  int r = blockIdx.x;                 // kpair = channel pair
  for (int m = threadIdx.x; m < 512; m += 256) {
    float b0 = (m < NSVD) ? bas[(size_t)(2 * r) * NSVD + m] : 0.f;
    float b1 = (m < NSVD) ? bas[(size_t)(2 * r + 1) * NSVD + m] : 0.f;
    unsigned h0 = bfr(b0), h1 = bfr(b1);
    int c = 1024 + m;
    size_t vi = ((size_t)((c >> 8) * 128 + (r >> 2)) * 256 + (c & 255)) * 4 + (r & 3);
    Ah[vi] = h0 | (h1 << 16);
    Al[vi] = bfr(lores(b0, h0)) | (bfr(lores(b1, h1)) << 16);
  }
}

// invc[s*HW+n] = 1/sqrt(max(1 - sum coef^2, 0))
__global__ __launch_bounds__(256) void normref_k(const float* __restrict__ coef,
                                                 float* __restrict__ invc) {
  int s = blockIdx.y;
  int n0 = blockIdx.x * 64;
  int tid = threadIdx.x, nl = tid & 63, r = tid >> 6;
  const float* base = coef + (size_t)s * 512 * HW + n0 + nl;
  float s2 = 0.f;
  for (int m = r; m < 512; m += 4) {
    float v = base[(size_t)m * HW];
    s2 += v * v;
  }
  __shared__ float red[256];
  red[tid] = s2;
  __syncthreads();
  if (r == 0) {
    float tot = red[nl] + red[nl + 64] + red[nl + 128] + red[nl + 192];
    invc[s * HW + n0 + nl] = 1.0f / fmaxf(sqrtf(fmaxf(1.0f - tot, 0.0f)), 1e-12f);
  }
}

// protos[s*CH+c] = sum_n mask*fn*invc; block = (s, kgrp of 8 channels)
__global__ __launch_bounds__(256) void proto_k(const unsigned* __restrict__ Gh,
                                               const unsigned* __restrict__ Gl,
                                               const int* __restrict__ mask,
                                               const float* __restrict__ invc,
                                               float* __restrict__ protos) {
  int s = blockIdx.x >> 7, kg = blockIdx.x & 127;
  int tid = threadIdx.x;
  const u32x4* Hv = (const u32x4*)Gh + (size_t)s * 524288;
  const u32x4* Lv = (const u32x4*)Gl + (size_t)s * 524288;
  float a[8] = {};
  for (int n = tid; n < HW; n += 256) {
    if (mask[s * HW + n]) {
      float w = invc[s * HW + n];
      size_t vi = ((size_t)(n >> 8) * 128 + kg) * 256 + (n & 255);
      u32x4 h = Hv[vi], l = Lv[vi];
#pragma unroll
      for (int j = 0; j < 4; j++) {
        a[2 * j] += vlo(h[j], l[j]) * w;
        a[2 * j + 1] += vhi(h[j], l[j]) * w;
      }
    }
  }
  __shared__ float red[256];
  for (int e = 0; e < 8; e++) {
    red[tid] = a[e];
    __syncthreads();
    for (int o = 128; o > 0; o >>= 1) {
      if (tid < o) red[tid] += red[tid + o];
      __syncthreads();
    }
    if (tid == 0) protos[s * CH + kg * 8 + e] = red[0];
    __syncthreads();
  }
}

// part[kc][s*CH+c] = sum_{r in kc-chunk} P[c][k]*protos[s][k]; grid (8, 8)
__global__ __launch_bounds__(256) void protomv_k(const unsigned* __restrict__ Ah,
                                                 const unsigned* __restrict__ Al,
                                                 const float* __restrict__ protos,
                                                 float* __restrict__ part) {
  int s = blockIdx.x >> 2;
  int c = (blockIdx.x & 3) * 256 + threadIdx.x;
  int kc = blockIdx.y;
  __shared__ float w[128];
  if (threadIdx.x < 128) w[threadIdx.x] = protos[s * CH + kc * 128 + threadIdx.x];
  __syncthreads();
  float acc = 0.f;
  for (int rl = 0; rl < 64; rl++) {
    int r = kc * 64 + rl;
    size_t vi = ((size_t)((c >> 8) * 128 + (r >> 2)) * 256 + (c & 255)) * 4 + (r & 3);
    unsigned h = Ah[vi], l = Al[vi];
    acc += vlo(h, l) * w[2 * rl] + vhi(h, l) * w[2 * rl + 1];
  }
  part[kc * 2048 + s * CH + c] = acc;
}

// counts + partial-sum reduce + mean + l2norm (1 block)
__global__ __launch_bounds__(256) void protonorm_k(const float* __restrict__ part,
                                                   const int* __restrict__ mask,
                                                   float* __restrict__ proto) {
  int tid = threadIdx.x;
  __shared__ float sm[CH];
  __shared__ float red[256];
  __shared__ float red2[256];
  int c0i = 0, c1i = 0;
  for (int i = tid; i < HW; i += 256) {
    c0i += (mask[i] != 0);
    c1i += (mask[HW + i] != 0);
  }
  red[tid] = (float)c0i;
  red2[tid] = (float)c1i;
  __syncthreads();
  for (int o = 128; o > 0; o >>= 1) {
    if (tid < o) { red[tid] += red[tid + o]; red2[tid] += red2[tid + o]; }
    __syncthreads();
  }
  float c0 = fmaxf(red[0], 1.0f), c1 = fmaxf(red2[0], 1.0f);
  __syncthreads();
  float ss = 0.f;
  for (int c = tid; c < CH; c += 256) {
    float p0 = 0.f, p1 = 0.f;
#pragma unroll
    for (int kc = 0; kc < 8; kc++) {
      p0 += part[kc * 2048 + c];
      p1 += part[kc * 2048 + CH + c];
    }
    float m = 0.5f * (p0 / c0 + p1 / c1);
    sm[c] = m;
    ss += m * m;
  }
  red[tid] = ss;
  __syncthreads();
  for (int o = 128; o > 0; o >>= 1) {
    if (tid < o) red[tid] += red[tid + o];
    __syncthreads();
  }
  __syncthreads();
  float inv = 1.0f / fmaxf(sqrtf(red[0]), 1e-12f);
  for (int c = tid; c < CH; c += 256) proto[c] = sm[c] * inv;
}

// sim_fwd: 64 blocks, 4-way kg split
__global__ __launch_bounds__(256) void simfwd_k(const unsigned* __restrict__ Gh,
                                                const unsigned* __restrict__ Gl,
                                                const float* __restrict__ proto,
                                                float* __restrict__ out) {
  __shared__ float p[CH];
  __shared__ float red[256];
  int tid = threadIdx.x;
  for (int c = tid; c < CH; c += 256) p[c] = proto[c];
  __syncthreads();
  int nl = tid & 63, q = tid >> 6;
  int n = blockIdx.x * 64 + nl;
  const u32x4* Hv = (const u32x4*)Gh + (size_t)2 * 524288;
  const u32x4* Lv = (const u32x4*)Gl + (size_t)2 * 524288;
  float acc = 0.f;
  for (int kg = q * 32; kg < q * 32 + 32; kg++) {
    size_t vi = ((size_t)(n >> 8) * 128 + kg) * 256 + (n & 255);
    u32x4 h = Hv[vi], l = Lv[vi];
#pragma unroll
    for (int j = 0; j < 4; j++)
      acc += vlo(h[j], l[j]) * p[8 * kg + 2 * j] + vhi(h[j], l[j]) * p[8 * kg + 2 * j + 1];
  }
  red[tid] = acc;
  __syncthreads();
  if (q == 0) out[n] = red[nl] + red[nl + 64] + red[nl + 128] + red[nl + 192];
}

// ---------------------------------------------------------------------------
// Debias GEMM (2-phase 128² kernel, blocked loads, full 3-pass).
// ---------------------------------------------------------------------------
#define BM 128
#define BK 32

__device__ __forceinline__ short8 ldfrag(const unsigned* S, int loc, int q) {
  return *reinterpret_cast<const short8*>(&S[loc * 32 + ((q ^ (loc & 7)) << 2)]);
}

__global__ __launch_bounds__(256) void gemm3d_k(
    const unsigned* __restrict__ Ach, const unsigned* __restrict__ Acl,
    const unsigned* __restrict__ fh, const unsigned* __restrict__ fl,
    float* __restrict__ Xd, float* __restrict__ coef) {
  int bx = blockIdx.x, bz = blockIdx.z;
  float* Cout;
  int m0 = bx * BM, cm0 = m0;
  if (bz == 2) {
    if (bx >= 8) return;
    Cout = Xd;
  } else {
    if (bx < 8) return;
    Cout = coef + (size_t)bz * 512 * HW;
    cm0 = (bx - 8) * BM;
  }
  int n0 = blockIdx.y * BM;
  const u32x4* Ahv = (const u32x4*)Ach;
  const u32x4* Alv = (const u32x4*)Acl;
  const u32x4* Bhv = (const u32x4*)fh + (size_t)bz * 524288;
  const u32x4* Blv = (const u32x4*)fl + (size_t)bz * 524288;

  __shared__ u32x4 AsV[BM * 8];
  __shared__ u32x4 BsV[BM * 8];
  unsigned* As = (unsigned*)AsV;
  unsigned* Bs = (unsigned*)BsV;

  int tid = threadIdx.x;
  int lane = tid & 63, wave = tid >> 6;
  int wr = wave >> 1, wc = wave & 1;
  int sn = tid & 127, kq = tid >> 7;
  int fcol = lane & 15, l16 = lane >> 4;

  int colA = m0 + sn, colB = n0 + sn;
  size_t ia = (size_t)(colA >> 8) * 32768 + (colA & 255);
  size_t ib = (size_t)(colB >> 8) * 32768 + (colB & 255);

  f32x4 acc[4][4] = {};
  unsigned rah[8], ral[8], rbh[8], rbl[8];

#define LOADT(KT)                                                          \
  {                                                                        \
    int g0 = (KT) * 4 + kq * 2;                                            \
    *reinterpret_cast<u32x4*>(&rah[0]) = Ahv[ia + (size_t)g0 * 256];       \
    *reinterpret_cast<u32x4*>(&rah[4]) = Ahv[ia + (size_t)(g0 + 1) * 256]; \
    *reinterpret_cast<u32x4*>(&ral[0]) = Alv[ia + (size_t)g0 * 256];       \
    *reinterpret_cast<u32x4*>(&ral[4]) = Alv[ia + (size_t)(g0 + 1) * 256]; \
    *reinterpret_cast<u32x4*>(&rbh[0]) = Bhv[ib + (size_t)g0 * 256];       \
    *reinterpret_cast<u32x4*>(&rbh[4]) = Bhv[ib + (size_t)(g0 + 1) * 256]; \
    *reinterpret_cast<u32x4*>(&rbl[0]) = Blv[ib + (size_t)g0 * 256];       \
    *reinterpret_cast<u32x4*>(&rbl[4]) = Blv[ib + (size_t)(g0 + 1) * 256]; \
  }

  LOADT(0);

  for (int kt = 0; kt < CH / BK; ++kt) {
    __syncthreads();
    {
      int xa = sn & 7;
      int q0 = ((2 * kq) ^ xa) << 2, q1 = ((2 * kq + 1) ^ xa) << 2;
      int q2 = ((4 + 2 * kq) ^ xa) << 2, q3 = ((5 + 2 * kq) ^ xa) << 2;
      *reinterpret_cast<u32x4*>(&As[sn * 32 + q0]) = *reinterpret_cast<u32x4*>(&rah[0]);
      *reinterpret_cast<u32x4*>(&As[sn * 32 + q1]) = *reinterpret_cast<u32x4*>(&rah[4]);
      *reinterpret_cast<u32x4*>(&As[sn * 32 + q2]) = *reinterpret_cast<u32x4*>(&ral[0]);
      *reinterpret_cast<u32x4*>(&As[sn * 32 + q3]) = *reinterpret_cast<u32x4*>(&ral[4]);
      *reinterpret_cast<u32x4*>(&Bs[sn * 32 + q0]) = *reinterpret_cast<u32x4*>(&rbh[0]);
      *reinterpret_cast<u32x4*>(&Bs[sn * 32 + q1]) = *reinterpret_cast<u32x4*>(&rbh[4]);
      *reinterpret_cast<u32x4*>(&Bs[sn * 32 + q2]) = *reinterpret_cast<u32x4*>(&rbl[0]);
      *reinterpret_cast<u32x4*>(&Bs[sn * 32 + q3]) = *reinterpret_cast<u32x4*>(&rbl[4]);
    }
    __syncthreads();

    if (kt + 1 < CH / BK) LOADT(kt + 1);

    short8 bhf[4], blf[4];
#pragma unroll
    for (int nf = 0; nf < 4; nf++) {
      int nloc = wc * 64 + nf * 16 + fcol;
      bhf[nf] = ldfrag(Bs, nloc, l16);
      blf[nf] = ldfrag(Bs, nloc, 4 + l16);
    }
#pragma unroll
    for (int mf = 0; mf < 4; mf++) {
      int mloc = wr * 64 + mf * 16 + fcol;
      short8 ah = ldfrag(As, mloc, l16);
      short8 al = ldfrag(As, mloc, 4 + l16);
#pragma unroll
      for (int nf = 0; nf < 4; nf++) {
        acc[mf][nf] = __builtin_amdgcn_mfma_f32_16x16x32_bf16(ah, bhf[nf], acc[mf][nf], 0, 0, 0);
        acc[mf][nf] = __builtin_amdgcn_mfma_f32_16x16x32_bf16(ah, blf[nf], acc[mf][nf], 0, 0, 0);
        acc[mf][nf] = __builtin_amdgcn_mfma_f32_16x16x32_bf16(al, bhf[nf], acc[mf][nf], 0, 0, 0);
      }
    }
  }
#undef LOADT

  int rbase = l16 * 4;
#pragma unroll
  for (int mf = 0; mf < 4; mf++) {
    int mbase = cm0 + wr * 64 + mf * 16 + rbase;
#pragma unroll
    for (int r = 0; r < 4; r++) {
#pragma unroll
      for (int nf = 0; nf < 4; nf++) {
        int n = n0 + wc * 64 + nf * 16 + fcol;
        Cout[(size_t)(mbase + r) * HW + n] = acc[mf][nf][r];
      }
    }
  }
}

// ---------------------------------------------------------------------------
// sim GEMM: 256x256 tile, 8 waves, 3-pass, phase-split + READ-AHEAD:
//   P0: MFMA ah*bh   | read bl(t)            | stage Al(t+1)
//   P1: MFMA ah*bl   | read al(t)            | stage Ah,Bh(t+2)
//   P2: MFMA al*bh   | read ah(t+1) (pre) + bh(t+1) (post) | stage Bl(t+2)
// Counted vmcnt {8,8,8} steady state; bit-identical accumulation to R10.
// ---------------------------------------------------------------------------
#define SIMG_NT 32

__global__ __launch_bounds__(512, 2) void simg_k(
    const unsigned* __restrict__ Gh, const unsigned* __restrict__ Gl,
    const float* __restrict__ invc, float* __restrict__ simout,
    unsigned long long* __restrict__ amg) {
  __shared__ __align__(16) unsigned smem[32768];   // 128 KB, 2 x 64 KB bufs

  int orig = (blockIdx.z * 16 + blockIdx.y) * 16 + blockIdx.x;
  int lin = (orig & 7) * 64 + (orig >> 3);         // XCD-contiguous, bijective
  int z = lin >> 8, bx = (lin >> 4) & 15, by = lin & 15;

  const unsigned* srcs[4];
  srcs[0] = Gh + (size_t)z * 2097152 + (size_t)bx * 131072;   // Ah -> slab 0
  srcs[1] = Gl + (size_t)z * 2097152 + (size_t)bx * 131072;   // Al -> slab 1
  srcs[2] = Gh + (size_t)2 * 2097152 + (size_t)by * 131072;   // Bh -> slab 2
  srcs[3] = Gl + (size_t)2 * 2097152 + (size_t)by * 131072;   // Bl -> slab 3

  int tid = threadIdx.x, ln = tid & 63, wv = tid >> 6;
  int wr = wv >> 2, wc = wv & 3;
  int fcol = ln & 15, l16 = ln >> 4;
  int aoff = l16 * 1024 + (wr * 128 + fcol) * 4;   // + mf*64
  int boff = l16 * 1024 + (wc * 64 + fcol) * 4;    // + nf*64

  f32x4 acc[8][4] = {};
  short8 ah[8], bh[4];

#define STAGE1(BSEL, T, OP)                                                   \
  {                                                                           \
    const unsigned* gs = srcs[OP] + (size_t)(T) * 4096;                       \
    _Pragma("unroll")                                                         \
    for (int rr = 0; rr < 2; rr++) {                                          \
      int off = rr * 2048 + tid * 4;                                          \
      __builtin_amdgcn_global_load_lds(                                       \
          (const __attribute__((address_space(1))) unsigned*)(gs + off),      \
          (__attribute__((address_space(3))) unsigned*)(smem + (BSEL) * 16384 + (OP) * 4096 + off), \
          16, 0, 0);                                                          \
    }                                                                         \
  }

#define MFMA32(A, B)                                                          \
  _Pragma("unroll")                                                           \
  for (int mf = 0; mf < 8; mf++)                                              \
    _Pragma("unroll")                                                         \
    for (int nf = 0; nf < 4; nf++)                                            \
      acc[mf][nf] = __builtin_amdgcn_mfma_f32_16x16x32_bf16(A[mf], B[nf], acc[mf][nf], 0, 0, 0);

  // prologue: queue = AhBh0(4) Bl0(2) Al0(2) AhBh1(4) Bl1(2) = 14
  STAGE1(0, 0, 0); STAGE1(0, 0, 2);
  STAGE1(0, 0, 3);
  STAGE1(0, 0, 1);
  STAGE1(1, 1, 0); STAGE1(1, 1, 2);
  STAGE1(1, 1, 3);
  asm volatile("s_waitcnt vmcnt(10)" ::: "memory");   // AhBh(0) landed
  __builtin_amdgcn_s_barrier();
  __builtin_amdgcn_sched_barrier(0);
#pragma unroll
  for (int mf = 0; mf < 8; mf++)
    ah[mf] = *reinterpret_cast<const short8*>(smem + aoff + mf * 64);
#pragma unroll
  for (int nf = 0; nf < 4; nf++)
    bh[nf] = *reinterpret_cast<const short8*>(smem + 8192 + boff + nf * 64);

  for (int t = 0; t < SIMG_NT; ++t) {
    const unsigned* Sb = smem + (t & 1) * 16384;
    const unsigned* Sn = smem + ((t + 1) & 1) * 16384;
    short8 bl[4], al[8];

    // -------- phase 0: MFMA ah*bh ; read-ahead bl(t) --------
    if (t < SIMG_NT - 1) asm volatile("s_waitcnt vmcnt(8)" ::: "memory");
    else                 asm volatile("s_waitcnt vmcnt(2)" ::: "memory");
    __builtin_amdgcn_s_barrier();
    __builtin_amdgcn_sched_barrier(0);
    if (t + 1 < SIMG_NT) STAGE1((t + 1) & 1, t + 1, 1);       // Al(t+1)
#pragma unroll
    for (int nf = 0; nf < 4; nf++)
      bl[nf] = *reinterpret_cast<const short8*>(Sb + 12288 + boff + nf * 64);
    __builtin_amdgcn_sched_barrier(0);
    __builtin_amdgcn_s_setprio(1);
    MFMA32(ah, bh)
    __builtin_amdgcn_s_setprio(0);

    // -------- phase 1: MFMA ah*bl ; read-ahead al(t) --------
    if (t < SIMG_NT - 1) asm volatile("s_waitcnt vmcnt(8)" ::: "memory");
    else                 asm volatile("s_waitcnt vmcnt(0)" ::: "memory");
    __builtin_amdgcn_s_barrier();
    __builtin_amdgcn_sched_barrier(0);
    if (t + 2 < SIMG_NT) { STAGE1(t & 1, t + 2, 0); STAGE1(t & 1, t + 2, 2); }
#pragma unroll
    for (int mf = 0; mf < 8; mf++)
      al[mf] = *reinterpret_cast<const short8*>(Sb + 4096 + aoff + mf * 64);
    __builtin_amdgcn_sched_barrier(0);
    __builtin_amdgcn_s_setprio(1);
    MFMA32(ah, bl)
    __builtin_amdgcn_s_setprio(0);

    // -------- phase 2: MFMA al*bh ; read-ahead ah(t+1), bh(t+1) --------
    if (t < SIMG_NT - 2)       asm volatile("s_waitcnt vmcnt(8)" ::: "memory");
    else if (t == SIMG_NT - 2) asm volatile("s_waitcnt vmcnt(4)" ::: "memory");
    __builtin_amdgcn_s_barrier();
    __builtin_amdgcn_sched_barrier(0);
    if (t + 2 < SIMG_NT) STAGE1(t & 1, t + 2, 3);             // Bl(t+2)
    if (t + 1 < SIMG_NT) {
#pragma unroll
      for (int mf = 0; mf < 8; mf++)
        ah[mf] = *reinterpret_cast<const short8*>(Sn + aoff + mf * 64);   // in-place: old ah dead
    }
    __builtin_amdgcn_sched_barrier(0);
    __builtin_amdgcn_s_setprio(1);
    MFMA32(al, bh)
    __builtin_amdgcn_s_setprio(0);
    if (t + 1 < SIMG_NT) {
#pragma unroll
      for (int nf = 0; nf < 4; nf++)
        bh[nf] = *reinterpret_cast<const short8*>(Sn + 8192 + boff + nf * 64);  // after last bh use
    }
  }
#undef STAGE1
#undef MFMA32

  // epilogue: row-scaled C write + fused column-argmax via packed atomicMax
  const float* rs = invc + (size_t)z * HW;
  float* C = simout + (size_t)z * HW * HW;
  unsigned long long* am = amg + (size_t)z * HW;
  int m0 = bx * 256, n0 = by * 256;
  int ncol[4];
#pragma unroll
  for (int nf = 0; nf < 4; nf++) ncol[nf] = n0 + wc * 64 + nf * 16 + fcol;
  float bv[4] = {-FLT_MAX, -FLT_MAX, -FLT_MAX, -FLT_MAX};
  int bi[4] = {0, 0, 0, 0};
#pragma unroll
  for (int mf = 0; mf < 8; mf++) {
    int mg = m0 + wr * 128 + mf * 16 + l16 * 4;
#pragma unroll
    for (int r = 0; r < 4; r++) {
      float sc = rs[mg + r];
#pragma unroll
      for (int nf = 0; nf < 4; nf++) {
        float val = acc[mf][nf][r] * sc;
        C[(size_t)(mg + r) * HW + ncol[nf]] = val;
        if (val > bv[nf]) { bv[nf] = val; bi[nf] = mg + r; }   // ascending m
      }
    }
  }
#pragma unroll
  for (int nf = 0; nf < 4; nf++) {
#pragma unroll
    for (int st = 16; st <= 32; st <<= 1) {
      float ov = __shfl_xor(bv[nf], st, 64);
      int oi = __shfl_xor(bi[nf], st, 64);
      if (ov > bv[nf] || (ov == bv[nf] && oi < bi[nf])) { bv[nf] = ov; bi[nf] = oi; }
    }
  }
  if (ln < 16) {
#pragma unroll
    for (int nf = 0; nf < 4; nf++) {
      unsigned b = __float_as_uint(bv[nf]);
      unsigned key = (b & 0x80000000u) ? ~b : (b | 0x80000000u);
      unsigned long long packed =
          ((unsigned long long)key << 32) | (unsigned)(~bi[nf]);
      atomicMax(am + ncol[nf], packed);
    }
  }
}

__global__ __launch_bounds__(256) void votes_k(const unsigned long long* __restrict__ am,
                                               const int* __restrict__ mask,
                                               float* __restrict__ out) {
  int xy = blockIdx.x * 256 + threadIdx.x;
  int vote = 0;
  for (int s = 0; s < SREF; s++) {
    unsigned long long p = am[(size_t)s * HW + xy];
    int bi = (int)(~(unsigned)p);
    vote += (mask[s * HW + bi] != 0);
  }
  out[xy] = (float)vote;
}

extern "C" void kernel_launch(void* const* d_in, const int* in_sizes, int n_in,
                              void* d_out, int out_size, void* d_ws, size_t ws_size,
                              hipStream_t stream) {
  const float* fmaps = (const float*)d_in[0];
  const int* mask = (const int*)d_in[1];
  const float* basis = (const float*)d_in[2];
  float* out = (float*)d_out;
  float* ws = (float*)d_ws;

  unsigned* fh = (unsigned*)ws;                       // blocked hi plane
  unsigned* fl = (unsigned*)(ws + 6291456);           // blocked lo plane
  float* invn = ws + 12582912;
  float* invc = ws + 12595200;
  float* protos = ws + 12607552;
  float* proto = ws + 12611648;
  unsigned long long* am = (unsigned long long*)(ws + 12612672);   // 2*HW u64
  float* part = ws + 12629056;                        // 8*2048 partials

  float* sim = out;
  float* simfwd = out + 33554432;
  float* votes = out + 33558528;
  unsigned* Ach = (unsigned*)out;                     // blocked Acomb (hi)
  unsigned* Acl = (unsigned*)(out + 786432);          // blocked Acomb (lo)
  float* coef = out + 1572864;
  float* Xd = out + 5767168;

  // 0) zero the packed-argmax array (graph-capture-safe)
  hipMemsetAsync(am, 0, (size_t)SREF * HW * sizeof(unsigned long long), stream);

  // 1) fn = l2norm(fmaps, C) -> blocked split planes (3 frames)
  colnorm_k<<<dim3(TFR * 64), 256, 0, stream>>>(fmaps, invn);
  scale_pack_k<<<dim3(TFR * 2048), 256, 0, stream>>>(fmaps, invn, fh, fl);

  // 2) blocked Acomb: projector + padded basis
  proj_pack_k<<<dim3(16, 16), 256, 0, stream>>>(basis, Ach, Acl);
  pack_basis_k<<<dim3(512), 256, 0, stream>>>(basis, Ach, Acl);

  // 3) batched debias: coef (z<2) + Xd (z=2), full 3-pass
  gemm3d_k<<<dim3(12, 32, 3), 256, 0, stream>>>(Ach, Acl, fh, fl, Xd, coef);
  normref_k<<<dim3(64, 2), 256, 0, stream>>>(coef, invc);

  // 4) tgt renorm + repack into planes frame 2
  colnorm_k<<<dim3(64), 256, 0, stream>>>(Xd, invc + 2 * HW);
  scale_pack_k<<<dim3(2048), 256, 0, stream>>>(Xd, invc + 2 * HW,
                                               fh + (size_t)2 * 2097152,
                                               fl + (size_t)2 * 2097152);

  // 5) prototype
  proto_k<<<256, 256, 0, stream>>>(fh, fl, mask, invc, protos);
  protomv_k<<<dim3(8, 8), 256, 0, stream>>>(Ach, Acl, protos, part);
  protonorm_k<<<1, 256, 0, stream>>>(part, mask, proto);

  // 6) sim_fwd
  simfwd_k<<<64, 256, 0, stream>>>(fh, fl, proto, simfwd);

  // 7) sim (256², 3-pass, read-ahead phase pipeline, fused atomic argmax)
  simg_k<<<dim3(16, 16, 2), 512, 0, stream>>>(fh, fl, invc, sim, am);

  // 8) votes
  votes_k<<<16, 256, 0, stream>>>(am, mask, votes);
}